// Round 7
// baseline (493.297 us; speedup 1.0000x reference)
//
#include <hip/hip_runtime.h>

typedef __attribute__((ext_vector_type(8))) short short8;
typedef __attribute__((ext_vector_type(4))) float f32x4;

constexpr int L = 1024, C = 256, F = 256;
constexpr int NIMG = 256;          // B*M
constexpr int LOUT = 1022;         // L - K + 1
constexpr long MAXROW = (long)NIMG * L - 1;

__device__ inline unsigned short f2bf(float f) {
  union { float f; unsigned u; } v; v.f = f;
  return (unsigned short)((v.u + 0x7FFFu + ((v.u >> 16) & 1u)) >> 16);  // RNE
}

// Pre-pass: W (3,256,256) fp32 -> Wt bf16, LINEAR layout [tile(slab*3+k)][f(256)][kp(32)]
// (R6's swizzle reverted: conflicts were fully hidden, swizzle cost +9%).
__global__ void wprep(const float* __restrict__ W, unsigned short* __restrict__ Wt) {
  int tid = blockIdx.x * 256 + threadIdx.x;       // exactly 768*256 threads
  int kc = tid >> 8, f = tid & 255;               // coalesced read of W[tid]
  int k = kc >> 8, c = kc & 255;
  int slab = c >> 5, kp = c & 31;
  Wt[(size_t)(((slab * 3 + k) * 256 + f) * 32 + kp)] = f2bf(W[tid]);
}

// R7: B bypasses LDS entirely. Wt (393 KB) is L2-resident; each wave loads its
// B fragments global->VGPR (coalesced dwordx4, 1 KB/instr), ping-pong buffers
// one tap ahead -- the compiler inserts exact counted vmcnt for register loads,
// so all manual vmcnt accounting disappears. LDS holds only A (8.4 KB/block);
// one barrier per slab (A-publish). Blocks are 4 waves (64Lx256F, wave 64x64,
// acc[4][4] = 64 AGPR): smaller barrier domains, graceful register-occupancy
// steps (4 blocks/CU at <=128 regs, 3 at <=170 -- no 8-wave cliff).
__global__ __launch_bounds__(256) void conv_mfma(
    const float* __restrict__ x, const unsigned short* __restrict__ Wt,
    const float* __restrict__ bias, float* __restrict__ y)
{
  __shared__ __align__(16) unsigned short As[2][264 * 8];  // 2 x 4224 B (66 rows x 32 bf16)

  const int bid = blockIdx.x;       // 4096 blocks
  const int lt  = bid & 15;         // 16 l-tiles of 64 rows over Lout=1022
  const int img = bid >> 4;         // 256 images
  const int l0  = lt * 64;

  const int tid  = threadIdx.x;
  const int lane = tid & 63;
  const int wc   = tid >> 6;        // 4 waves, one 64x64 tile each across F
  const int lr   = lane & 15;
  const int quad = lane >> 4;

  f32x4 acc[4][4] = {};
  float4 av[2];                     // A chunk tid (rows 0..63 of tile, 1 chunk/thread)
  float4 avt[2];                    // tail chunks 256..263 (tid < 8: rows 64,65)
  short8 bfA[4], bfB[4];            // B fragment ping-pong (global->VGPR)

  const long gb = (long)img * L + l0;

  auto issue_A = [&](int slab) {    // global -> regs, rows 0..65 of slab (fp32)
    const int cb = slab * 32;
    long g0 = gb + (tid >> 2); if (g0 > MAXROW) g0 = MAXROW;   // clamped rows feed
    const float* p0 = x + g0 * C + cb + (tid & 3) * 8;         // only masked outputs
    av[0] = *(const float4*)p0; av[1] = *(const float4*)(p0 + 4);
    if (tid < 8) {
      long g2 = gb + 64 + (tid >> 2); if (g2 > MAXROW) g2 = MAXROW;
      const float* p2 = x + g2 * C + cb + (tid & 3) * 8;
      avt[0] = *(const float4*)p2; avt[1] = *(const float4*)(p2 + 4);
    }
  };

  auto pack8 = [&](float4 a, float4 b) {
    short8 r;
    r[0] = (short)f2bf(a.x); r[1] = (short)f2bf(a.y);
    r[2] = (short)f2bf(a.z); r[3] = (short)f2bf(a.w);
    r[4] = (short)f2bf(b.x); r[5] = (short)f2bf(b.y);
    r[6] = (short)f2bf(b.z); r[7] = (short)f2bf(b.w);
    return r;
  };

  auto write_A = [&](int ab2) {     // 264 chunks of 16 B, contiguous -> balanced
    *(short8*)(As[ab2] + (size_t)tid * 8) = pack8(av[0], av[1]);
    if (tid < 8)
      *(short8*)(As[ab2] + (size_t)(256 + tid) * 8) = pack8(avt[0], avt[1]);
  };

  // B fragment loads: lane (quad,lr) reads Wt[tile][wc*64+ni*16+lr][quad*8..+8]
  // = 16 B; per instruction the wave covers a contiguous 1 KB block of Wt.
#define LOADB(dst, tile)                                                      \
  do {                                                                        \
    _Pragma("unroll")                                                         \
    for (int ni = 0; ni < 4; ++ni)                                            \
      dst[ni] = *(const short8*)(Wt +                                         \
          ((size_t)(tile) * 256 + wc * 64 + ni * 16 + lr) * 32 + quad * 8);   \
  } while (0)

  // One tap: issue next tap's B loads (overlap), ds_read A frags (compiler
  // inserts exact lgkmcnt), 16 MFMA on the current B buffer (compiler inserts
  // exact counted vmcnt for bfC's loads -- leaves the just-issued 4 in flight).
#define TAP(bfC, bfN, ntile, kk, ab)                                          \
  do {                                                                        \
    if ((ntile) >= 0) LOADB(bfN, (ntile));                                    \
    short8 af[4];                                                             \
    _Pragma("unroll")                                                         \
    for (int mi = 0; mi < 4; ++mi)                                            \
      af[mi] = *(const short8*)(As[ab] + ((mi * 16 + lr + (kk)) * 4 + quad) * 8); \
    __builtin_amdgcn_s_setprio(1);                                            \
    _Pragma("unroll")                                                         \
    for (int mi = 0; mi < 4; ++mi)                                            \
      _Pragma("unroll")                                                       \
      for (int ni = 0; ni < 4; ++ni)                                          \
        acc[mi][ni] = __builtin_amdgcn_mfma_f32_16x16x32_bf16(                \
            af[mi], bfC[ni], acc[mi][ni], 0, 0, 0);                           \
    __builtin_amdgcn_s_setprio(0);                                            \
  } while (0)

  // Buffer invariant: at slab-s top, buffer parity (s&1) holds tile 3s.
  // tap0 consumes P, loads P^1 <- 3s+1; tap1 consumes P^1, loads P <- 3s+2;
  // tap2 consumes P, loads P^1 <- 3s+3 (next slab's tile 0). Holds inductively.
#define SLAB(P0, P1, s)                                                       \
  do {                                                                        \
    if ((s) < 7) issue_A((s) + 1);                                            \
    TAP(P0, P1, 3 * (s) + 1, 0, (s) & 1);                                     \
    TAP(P1, P0, 3 * (s) + 2, 1, (s) & 1);                                     \
    TAP(P0, P1, ((s) < 7 ? 3 * (s) + 3 : -1), 2, (s) & 1);                    \
    if ((s) < 7) {                                                            \
      write_A(((s) & 1) ^ 1);      /* pack waits av via compiler */           \
      asm volatile("s_waitcnt lgkmcnt(0)" ::: "memory");  /* publish writes */\
      __builtin_amdgcn_s_barrier();                                           \
      __builtin_amdgcn_sched_barrier(0);                                      \
    }                                                                         \
  } while (0)

  // ---- prologue: A(0) loaded+packed+published; B tile 0 in flight to bfA
  issue_A(0);
  LOADB(bfA, 0);
  write_A(0);
  asm volatile("s_waitcnt lgkmcnt(0)" ::: "memory");
  __builtin_amdgcn_s_barrier();
  __builtin_amdgcn_sched_barrier(0);

#pragma unroll
  for (int s = 0; s < 8; ++s) {
    if ((s & 1) == 0) SLAB(bfA, bfB, s);
    else              SLAB(bfB, bfA, s);
  }

  // Epilogue: C/D layout col=lane&15, row=quad*4+reg (m89/m91-verified)
  float bv[4];
#pragma unroll
  for (int ni = 0; ni < 4; ++ni)
    bv[ni] = bias[wc * 64 + ni * 16 + lr];

#pragma unroll
  for (int mi = 0; mi < 4; ++mi) {
#pragma unroll
    for (int r = 0; r < 4; ++r) {
      const int lrow = l0 + mi * 16 + quad * 4 + r;
      if (lrow < LOUT) {
        float* yp = y + ((size_t)img * LOUT + lrow) * F + wc * 64 + lr;
#pragma unroll
        for (int ni = 0; ni < 4; ++ni)
          yp[ni * 16] = acc[mi][ni][r] + bv[ni];
      }
    }
  }
#undef SLAB
#undef TAP
#undef LOADB
}

extern "C" void kernel_launch(void* const* d_in, const int* in_sizes, int n_in,
                              void* d_out, int out_size, void* d_ws, size_t ws_size,
                              hipStream_t stream) {
  const float* x = (const float*)d_in[0];   // (8,32,1024,256) fp32
  const float* W = (const float*)d_in[1];   // (3,256,256) fp32
  const float* b = (const float*)d_in[2];   // (256,) fp32
  float* y = (float*)d_out;                 // (8,32,1022,256) fp32
  unsigned short* Wt = (unsigned short*)d_ws;  // 3*256*256*2 = 393,216 B

  wprep<<<768, 256, 0, stream>>>(W, Wt);
  conv_mfma<<<NIMG * 16, 256, 0, stream>>>(x, Wt, b, y);
}